// Round 5
// baseline (253.424 us; speedup 1.0000x reference)
//
#include <hip/hip_runtime.h>

// AttentionLayer: N=8, L=1024, D_MODEL=1024, H=16, d_head=64.
// out  = softmax(QK^T/8)V reshaped   (8,1024,1024) fp32
// attn = mean over heads of softmax  (8,1024,1024) fp32, after out.
//
// R10: permuted K fragments eliminated the P LDS round-trip (bank conflicts
//      3.1M -> 0, VALU 32->25%) but dur unchanged 185->180us: P chain was
//      not critical. ~65% of cycles are stalls; K/V global loads have only
//      ~1 fragment of slack vs ~200-400cy L2 latency (4MB working set = L2
//      size per XCD), and 4 waves/SIMD can't cover it with TLP.
// R11: prefetch distance. Loop1: V double-buffered (vA/vB), loaded 2
//      windows ahead (explicit window-pair unroll for static names).
//      Loop2: kw ping-pong -- next window's loads issued before the
//      barrier+reduce so they hide under it; reduce uses paired b32 LDS
//      reads (16 vs 32 per thread) and float2 stores. VGPR ~120 < 128 cap.
// ws: 32 MB (bKw + bTw).

#define NB 8
#define LQ 1024
#define DM 1024
#define NH 16
#define DH 64
#define AW 68           // attn stage row stride (shorts): 136 B

typedef __attribute__((ext_vector_type(4))) float f32x4;
typedef __attribute__((ext_vector_type(2))) float f32x2;
typedef __attribute__((ext_vector_type(8))) short bf16x8;
typedef __attribute__((ext_vector_type(4))) short bf16x4;
typedef __attribute__((ext_vector_type(4))) int   i32x4;
typedef __attribute__((ext_vector_type(2))) int   i32x2;

__device__ inline short f2bf(float f){
  unsigned u = __builtin_bit_cast(unsigned, f);
  u += 0x7fffu + ((u >> 16) & 1u);   // RNE (inputs finite)
  return (short)(u >> 16);
}
__device__ inline float bf2f(short s){
  unsigned u = ((unsigned)(unsigned short)s) << 16;
  return __builtin_bit_cast(float, u);
}
__device__ inline int cvt_pk_bf16(float lo, float hi){
  int r;
  asm("v_cvt_pk_bf16_f32 %0, %1, %2" : "=v"(r) : "v"(lo), "v"(hi));
  return r;
}

// ---------------- k0: fp32 -> bf16 into MFMA-friendly layouts ---------------
__global__ __launch_bounds__(256) void k0_convert(const float* __restrict__ in,
                                                  short* __restrict__ bKw,
                                                  short* __restrict__ bTw){
  __shared__ short tile[32][36];
  int b  = blockIdx.x;
  int n  = b >> 10;
  int lt = (b >> 5) & 31;          // s-tile of 32 == V window index
  int dt = b & 31;                 // d-tile of 32: head = dt>>1, half = dt&1
  int r  = threadIdx.x >> 3;       // 0..31
  int c4 = (threadIdx.x & 7) << 2; // 0,4,...,28
  size_t src = ((size_t)(n*LQ + lt*32 + r))*DM + dt*32 + c4;
  f32x4 f = *(const f32x4*)(in + src);
  short s0 = f2bf(f.x), s1 = f2bf(f.y), s2 = f2bf(f.z), s3 = f2bf(f.w);
  // head-major K/Q: bKw[((n*16 + h)*1024 + s)*64 + (dt&1)*32 + c]
  bf16x4 pk = {s0, s1, s2, s3};
  size_t kdst = ((size_t)((n*NH + (dt >> 1))*LQ + lt*32 + r))*DH + (dt & 1)*32 + c4;
  *(bf16x4*)(bKw + kdst) = pk;
  // transpose for V
  tile[c4+0][r] = s0; tile[c4+1][r] = s1; tile[c4+2][r] = s2; tile[c4+3][r] = s3;
  __syncthreads();
  bf16x4 t = *(const bf16x4*)(&tile[r][c4]);
  // win-tiled V: bTw[((n*32 + lt)*1024 + dt*32 + r)*32 + sl]
  size_t vdst = ((size_t)((n*32 + lt)*DM + dt*32 + r))*32 + c4;
  *(bf16x4*)(bTw + vdst) = t;
}

// ---------------- k2: one wave per head, two q-tiles per wave ---------------
// LDS arena AS[2][NH*16*AW] shorts (69632 B): loop2 attn staging only.
__global__ __launch_bounds__(1024, 4) void k2_attn(const short* __restrict__ bKw,
                                                   const short* __restrict__ bTw,
                                                   float* __restrict__ out,
                                                   float* __restrict__ attn){
  __shared__ short AS[2*NH*16*AW];      // 69632 B
  int tid  = threadIdx.x;
  int lane = tid & 63;
  int w    = tid >> 6;                  // wave id == head id
  int l16  = lane & 15;
  int quad = lane >> 4;
  int n  = blockIdx.x & 7;              // XCD swizzle: all blocks on XCD x share n=x
  int q0 = (blockIdx.x >> 3) << 5;      // 32 q-rows per block

  const float CE = 0.1803368801111244f; // 0.125 * log2(e)
  const f32x4 vzero = {0.f, 0.f, 0.f, 0.f};

  size_t hb = ((size_t)(n*NH + w))*LQ*DH;
  // standard fragment base (Q loads, loop2 K loads): row s -> kb + s*64
  const short* kb  = bKw + hb + (size_t)l16*DH + quad*8;
  // permuted fragment base (loop1 K loads): lane l16=r supplies row (r>>2)*8+(r&3)
  const short* kbp = bKw + hb + (size_t)((l16 >> 2)*8 + (l16 & 3))*DH + quad*8;

  bf16x8 qfA0 = *(const bf16x8*)(kb + (size_t)q0*DH);
  bf16x8 qfA1 = *(const bf16x8*)(kb + (size_t)q0*DH + 32);
  bf16x8 qfB0 = *(const bf16x8*)(kb + (size_t)(q0+16)*DH);
  bf16x8 qfB1 = *(const bf16x8*)(kb + (size_t)(q0+16)*DH + 32);

  f32x4 oaccA[4], oaccB[4];
  #pragma unroll
  for (int dt = 0; dt < 4; ++dt){ oaccA[dt] = vzero; oaccB[dt] = vzero; }
  float rsumA = 0.f, rsumB = 0.f;

  // ---- loop1: QK + exp (unnormalized) + PV, no barriers, no LDS ----
  // fragment f: s-offset t = (f>>1)*32 + (f&1)*4. window w: frags 2w, 2w+1.
  // V ping-pong: vA/vB hold windows 2i / 2i+1, reloaded 2 windows ahead.

#define LOADK(D0, D1, T) do {                                   \
    const short* _p = kbp + (size_t)(T)*DH;                     \
    D0 = *(const bf16x8*)_p; D1 = *(const bf16x8*)(_p + 32);    \
  } while(0)

#define LOADV(DST, WIN) do {                                    \
    int _vw = (WIN) & 31;                                       \
    _Pragma("unroll")                                           \
    for (int dt = 0; dt < 4; ++dt){                             \
      DST[dt] = *(const bf16x8*)(bTw +                          \
        ((size_t)((n*32 + _vw)*DM + w*DH + dt*16 + l16))*32 + quad*8); \
    }                                                           \
  } while(0)

#define QKEXP(K0, K1, DA0, DA1, DB0, DB1) do {                          \
    f32x4 stA = vzero, stB = vzero;                                     \
    stA = __builtin_amdgcn_mfma_f32_16x16x32_bf16(K0, qfA0, stA, 0,0,0);\
    stA = __builtin_amdgcn_mfma_f32_16x16x32_bf16(K1, qfA1, stA, 0,0,0);\
    stB = __builtin_amdgcn_mfma_f32_16x16x32_bf16(K0, qfB0, stB, 0,0,0);\
    stB = __builtin_amdgcn_mfma_f32_16x16x32_bf16(K1, qfB1, stB, 0,0,0);\
    float eA0 = __builtin_amdgcn_exp2f(stA[0]*CE);                      \
    float eA1 = __builtin_amdgcn_exp2f(stA[1]*CE);                      \
    float eA2 = __builtin_amdgcn_exp2f(stA[2]*CE);                      \
    float eA3 = __builtin_amdgcn_exp2f(stA[3]*CE);                      \
    float eB0 = __builtin_amdgcn_exp2f(stB[0]*CE);                      \
    float eB1 = __builtin_amdgcn_exp2f(stB[1]*CE);                      \
    float eB2 = __builtin_amdgcn_exp2f(stB[2]*CE);                      \
    float eB3 = __builtin_amdgcn_exp2f(stB[3]*CE);                      \
    rsumA += (eA0 + eA1) + (eA2 + eA3);                                 \
    rsumB += (eB0 + eB1) + (eB2 + eB3);                                 \
    DA0 = cvt_pk_bf16(eA0, eA1); DA1 = cvt_pk_bf16(eA2, eA3);           \
    DB0 = cvt_pk_bf16(eB0, eB1); DB1 = cvt_pk_bf16(eB2, eB3);           \
  } while(0)

#define PVSTEP(VB, PA0, PA1, PA2, PA3, PB0, PB1, PB2, PB3) do {         \
    i32x4 _ta = {PA0, PA1, PA2, PA3};                                   \
    i32x4 _tb = {PB0, PB1, PB2, PB3};                                   \
    bf16x8 _aA = __builtin_bit_cast(bf16x8, _ta);                       \
    bf16x8 _aB = __builtin_bit_cast(bf16x8, _tb);                       \
    _Pragma("unroll")                                                   \
    for (int dt = 0; dt < 4; ++dt){                                     \
      oaccA[dt] = __builtin_amdgcn_mfma_f32_16x16x32_bf16(_aA, VB[dt], oaccA[dt], 0,0,0); \
      oaccB[dt] = __builtin_amdgcn_mfma_f32_16x16x32_bf16(_aB, VB[dt], oaccB[dt], 0,0,0); \
    }                                                                   \
  } while(0)

  {
    bf16x8 kf0, kf1, nk0, nk1;
    bf16x8 vA[4], vB[4];
    LOADK(kf0, kf1, 0);                 // frag 0 (t=0)
    LOADV(vA, 0);
    LOADV(vB, 1);
    int paA0, paA1, paB0, paB1, dA0, dA1, dB0, dB1;
    for (int i = 0; i < 16; ++i){       // window pair (2i, 2i+1)
      int t0 = i*64;
      // frag 4i (t0): even half of window 2i
      LOADK(nk0, nk1, t0 + 4);
      QKEXP(kf0, kf1, paA0, paA1, paB0, paB1);
      kf0 = nk0; kf1 = nk1;
      // frag 4i+1 (t0+4): odd half -> PV window 2i (vA)
      LOADK(nk0, nk1, t0 + 32);
      QKEXP(kf0, kf1, dA0, dA1, dB0, dB1);
      PVSTEP(vA, paA0, paA1, dA0, dA1, paB0, paB1, dB0, dB1);
      LOADV(vA, 2*i + 2);               // reload vA 2 windows ahead
      kf0 = nk0; kf1 = nk1;
      // frag 4i+2 (t0+32): even half of window 2i+1
      LOADK(nk0, nk1, t0 + 36);
      QKEXP(kf0, kf1, paA0, paA1, paB0, paB1);
      kf0 = nk0; kf1 = nk1;
      // frag 4i+3 (t0+36): odd half -> PV window 2i+1 (vB)
      LOADK(nk0, nk1, (t0 + 64) & 1023);
      QKEXP(kf0, kf1, dA0, dA1, dB0, dB1);
      PVSTEP(vB, paA0, paA1, dA0, dA1, paB0, paB1, dB0, dB1);
      LOADV(vB, 2*i + 3);               // reload vB 2 windows ahead
      kf0 = nk0; kf1 = nk1;
    }
  }

  // softmax normalizer for q = l16 (full row sum across quads)
  rsumA += __shfl_xor(rsumA, 16);
  rsumA += __shfl_xor(rsumA, 32);
  rsumB += __shfl_xor(rsumB, 16);
  rsumB += __shfl_xor(rsumB, 32);
  float irA  = 1.0f / rsumA;
  float irB  = 1.0f / rsumB;
  float irsA = irA * 0.0625f;           // folded 1/NH for attn
  float irsB = irB * 0.0625f;

  // ---- O epilogue: oacc rows are q = quad*4 + j -> need ir of that q ----
  float irqA[4], irqB[4];
  #pragma unroll
  for (int j = 0; j < 4; ++j){
    irqA[j] = __shfl(irA, quad*4 + j);
    irqB[j] = __shfl(irB, quad*4 + j);
  }
  #pragma unroll
  for (int dt = 0; dt < 4; ++dt){
    float* opA = out + ((size_t)(n*LQ + q0 + quad*4))*DM + w*DH + dt*16 + l16;
    opA[0]      = oaccA[dt][0] * irqA[0];
    opA[DM]     = oaccA[dt][1] * irqA[1];
    opA[2*DM]   = oaccA[dt][2] * irqA[2];
    opA[3*DM]   = oaccA[dt][3] * irqA[3];
    float* opB = opA + (size_t)16*DM;
    opB[0]      = oaccB[dt][0] * irqB[0];
    opB[DM]     = oaccB[dt][1] * irqB[1];
    opB[2*DM]   = oaccB[dt][2] * irqB[2];
    opB[3*DM]   = oaccB[dt][3] * irqB[3];
  }

  // ---- loop2: recompute QK per 64-s window, bf16 stage + paired reduce ----
  short* AmineA = &AS[w*16*AW];
  short* AmineB = &AS[NH*16*AW + w*16*AW];

#define LOADKW(DST, WIN) do {                                   \
    int _w15 = (WIN) & 15;                                      \
    _Pragma("unroll")                                           \
    for (int sub = 0; sub < 4; ++sub){                          \
      const short* _kp = kb + (size_t)(_w15*64 + sub*16)*DH;    \
      DST[sub][0] = *(const bf16x8*)_kp;                        \
      DST[sub][1] = *(const bf16x8*)(_kp + 32);                 \
    }                                                           \
  } while(0)

#define STAGE(KW) do {                                                  \
    _Pragma("unroll")                                                   \
    for (int sub = 0; sub < 4; ++sub){                                  \
      f32x4 stA = vzero, stB = vzero;                                   \
      stA = __builtin_amdgcn_mfma_f32_16x16x32_bf16(KW[sub][0], qfA0, stA, 0,0,0); \
      stA = __builtin_amdgcn_mfma_f32_16x16x32_bf16(KW[sub][1], qfA1, stA, 0,0,0); \
      stB = __builtin_amdgcn_mfma_f32_16x16x32_bf16(KW[sub][0], qfB0, stB, 0,0,0); \
      stB = __builtin_amdgcn_mfma_f32_16x16x32_bf16(KW[sub][1], qfB1, stB, 0,0,0); \
      float gA0 = __builtin_amdgcn_exp2f(stA[0]*CE) * irsA;             \
      float gA1 = __builtin_amdgcn_exp2f(stA[1]*CE) * irsA;             \
      float gA2 = __builtin_amdgcn_exp2f(stA[2]*CE) * irsA;             \
      float gA3 = __builtin_amdgcn_exp2f(stA[3]*CE) * irsA;             \
      float gB0 = __builtin_amdgcn_exp2f(stB[0]*CE) * irsB;             \
      float gB1 = __builtin_amdgcn_exp2f(stB[1]*CE) * irsB;             \
      float gB2 = __builtin_amdgcn_exp2f(stB[2]*CE) * irsB;             \
      float gB3 = __builtin_amdgcn_exp2f(stB[3]*CE) * irsB;             \
      i32x2 wvA = {cvt_pk_bf16(gA0, gA1), cvt_pk_bf16(gA2, gA3)};       \
      i32x2 wvB = {cvt_pk_bf16(gB0, gB1), cvt_pk_bf16(gB2, gB3)};       \
      *(i32x2*)(&AmineA[l16*AW + sub*16 + quad*4]) = wvA;               \
      *(i32x2*)(&AmineB[l16*AW + sub*16 + quad*4]) = wvB;               \
    }                                                                   \
  } while(0)

#define REDUCE(WIN) do {                                                \
    int _tile = tid >> 9;               /* 0..1 */                      \
    int _qr   = (tid >> 5) & 15;        /* 0..15 */                     \
    int _s2   = tid & 31;               /* s pair: s = 2*_s2 */         \
    int _base = _tile*NH*16*AW + _qr*AW + 2*_s2;                        \
    float _s0 = 0.f, _s1 = 0.f;                                         \
    _Pragma("unroll")                                                   \
    for (int ww = 0; ww < NH; ++ww){                                    \
      int _v = *(const int*)(&AS[_base + ww*16*AW]);                    \
      _s0 += bf2f((short)(_v & 0xffff));                                \
      _s1 += bf2f((short)((unsigned)_v >> 16));                         \
    }                                                                   \
    f32x2 _o = {_s0, _s1};                                              \
    *(f32x2*)(&attn[((size_t)(n*LQ + q0 + _tile*16 + _qr))*LQ + (WIN)*64 + 2*_s2]) = _o; \
  } while(0)

  {
    bf16x8 kwA[4][2], kwB[4][2];
    LOADKW(kwA, 0);
    for (int wp = 0; wp < 8; ++wp){
      int win0 = 2*wp, win1 = 2*wp + 1;
      STAGE(kwA);
      LOADKW(kwB, win1);                // hide under barrier+reduce
      __syncthreads();
      REDUCE(win0);
      __syncthreads();
      STAGE(kwB);
      LOADKW(kwA, win1 + 1);            // win 16 wraps to 0: harmless
      __syncthreads();
      REDUCE(win1);
      __syncthreads();
    }
  }
}

extern "C" void kernel_launch(void* const* d_in, const int* in_sizes, int n_in,
                              void* d_out, int out_size, void* d_ws, size_t ws_size,
                              hipStream_t stream){
  const float* in = (const float*)d_in[0];
  float* out  = (float*)d_out;
  float* attn = out + (size_t)NB*LQ*DM;
  short* bKw = (short*)d_ws;
  short* bTw = bKw + (size_t)NB*LQ*DM;

  k0_convert<<<dim3(8192), dim3(256),  0, stream>>>(in, bKw, bTw);
  k2_attn   <<<dim3(256),  dim3(1024), 0, stream>>>(bKw, bTw, out, attn);
}